// Round 9
// baseline (481.312 us; speedup 1.0000x reference)
//
#include <hip/hip_runtime.h>
#include <hip/hip_bf16.h>
#include <math.h>

// Problem constants
#define NB 256   // graphs
#define NN 2048  // nodes
#define NR 64    // roots
#define ND 64    // embed dim
#define NT 8     // node types
#define NTH 512  // threads per block (8 waves: one wave per node type)
#define NW 8     // waves per block
#define XP 136   // hs row stride in shorts (272 B = 17*16: aligned, conflict-benign)
#define SROWS 256 // frontier stash rows per buffer
#define SP 72    // stash row stride in shorts (144 B: 16B-aligned, conflict-benign)

typedef __attribute__((ext_vector_type(8))) short short8;
typedef __attribute__((ext_vector_type(4))) float f32x4;

__device__ __forceinline__ unsigned short f2bf(float f) {
    unsigned u = __float_as_uint(f);
    return (unsigned short)((u + 0x7fffu + ((u >> 16) & 1u)) >> 16);
}

// Packed RNE f32x2 -> bf16x2 (v_cvt_pk_bf16_f32; bit-identical to f2bf pairs).
__device__ __forceinline__ unsigned pk2bf(float a, float b) {
    __hip_bfloat162 h = __float22bfloat162_rn(float2{a, b});
    unsigned r; __builtin_memcpy(&r, &h, 4); return r;
}

__device__ __forceinline__ short8 cvt8(float4 a, float4 b) {
    union { short8 s; unsigned u[4]; } v;
    v.u[0] = pk2bf(a.x, a.y); v.u[1] = pk2bf(a.z, a.w);
    v.u[2] = pk2bf(b.x, b.y); v.u[3] = pk2bf(b.z, b.w);
    return v.s;
}

// Fast GELU via A&S 7.1.25 3-term erf (|err| <= 2.5e-5 — invisible under
// bf16-weight quantization noise). ~10 VALU + 2 trans.
__device__ __forceinline__ float fast_gelu(float v) {
    const float ax = fabsf(v) * 0.70710678118654752f;
    const float t  = __builtin_amdgcn_rcpf(fmaf(0.47047f, ax, 1.0f));
    float p = fmaf(0.7478556f, t, -0.0958798f);
    p = fmaf(p, t, 0.3480242f);
    p *= t;
    const float e  = exp2f(ax * ax * -1.4426950408889634f); // exp(-x^2)
    const float er = fmaf(-p, e, 1.0f);                     // erf(|x|)
    const float es = copysignf(er, v);
    const float hv = 0.5f * v;
    return fmaf(hv, es, hv);                                // 0.5v(1+erf)
}

// ---------------------------------------------------------------------------
// Pre-kernel: transpose weights to [type][out][in] bf16 (RNE).
// ---------------------------------------------------------------------------
__global__ void convert_weights(const float* __restrict__ W1,
                                const float* __restrict__ W2,
                                unsigned short* __restrict__ w1t,
                                unsigned short* __restrict__ w2t) {
    int g = blockIdx.x * 256 + threadIdx.x;
    if (g < NT * 128 * 128) {
        int t = g >> 14, r = g & 16383, j = r >> 7, i = r & 127;
        w1t[g] = f2bf(W1[(t * 128 + i) * 128 + j]);
    }
    if (g < NT * 64 * 128) {
        int t = g >> 13, r = g & 8191, d = r >> 7, jj = r & 127;
        w2t[g] = f2bf(W2[(t * 128 + jj) * 64 + d]);
    }
}

// Inclusive block scan of arr[0..2048) via wave shuffles: 3 barriers.
__device__ __forceinline__ void block_scan2048(unsigned* __restrict__ arr,
                                               unsigned* __restrict__ csum,
                                               int w, int lane) {
    for (int c = w; c < 32; c += NW) {
        unsigned v = arr[c * 64 + lane];
        #pragma unroll
        for (int off = 1; off < 64; off <<= 1) {
            unsigned u = __shfl_up(v, off, 64);
            if (lane >= off) v += u;
        }
        arr[c * 64 + lane] = v;
        if (lane == 63) csum[c] = v;
    }
    __syncthreads();
    if (w == 0) {
        unsigned s = (lane < 32) ? csum[lane] : 0u;
        #pragma unroll
        for (int off = 1; off < 32; off <<= 1) {
            unsigned u = __shfl_up(s, off, 64);
            if (lane >= off) s += u;
        }
        if (lane < 32) csum[lane] = s;
    }
    __syncthreads();
    for (int c = w; c < 32; c += NW)
        if (c > 0) arr[c * 64 + lane] += csum[c - 1];
    __syncthreads();
}

// ---------------------------------------------------------------------------
// One block (512 thr, 8 waves) per graph. Wave w owns node type t=w (weights
// + biases register-resident). Per level: wave w processes bucket key=L*8+w.
// Latency engineering: (a) level-L outputs also stored bf16 into a
// double-buffered LDS frontier stash -> next level's hot parents (depth==L)
// read LDS, not L3/HBM; (b) cold parents (depth<=L-1) of the NEXT level's
// tile are prefetched into registers before the barrier (latency hidden
// under MFMA+GELU). keys[] is repurposed post-scatter as node->listpos for
// stash slot lookup.
// ---------------------------------------------------------------------------
__global__ __launch_bounds__(NTH, 2)
void dag_encoder_kernel(const float* __restrict__ roots,
                        const float* __restrict__ b1,
                        const float* __restrict__ b2,
                        const int*   __restrict__ idxs,
                        const int*   __restrict__ types,
                        float* __restrict__ out,
                        const unsigned short* __restrict__ w1t,
                        const unsigned short* __restrict__ w2t)
{
    __shared__ unsigned int   depth[NN];        // 8 KB (preserved through exec)
    __shared__ unsigned short keys[NN];         // 4 KB (post-scatter: node->listpos)
    __shared__ unsigned int   scanA[NN];        // 8 KB (inclusive key-count scan)
    __shared__ unsigned int   curs[NN];         // 8 KB (scatter cursors)
    __shared__ unsigned short list[NN];         // 4 KB (nodes sorted by key)
    __shared__ unsigned int   listP[NN];        // 8 KB (parent pairs, key-sorted)
    __shared__ __align__(4) unsigned short parv[2 * NN];  // 8 KB
    __shared__ unsigned int   csum[32];
    __shared__ __align__(16) unsigned short hs[NW][16][XP];       // 34 KB
    __shared__ __align__(16) unsigned short stash[2][SROWS][SP];  // 72 KB
    __shared__ int s_maxd;

    const int b    = blockIdx.x;
    const int tid  = threadIdx.x;
    const int w    = tid >> 6;     // wave id == owned node type
    const int lane = tid & 63;
    const int q    = lane >> 4;
    const int l    = lane & 15;

    float* gbuf = out + (size_t)b * NN * ND;
    const int* gtyp = types + (size_t)b * NN;
    const int* gi   = idxs  + (size_t)b * NN * 2;

    // ---- roots -> gbuf; parents -> LDS; depth init ----
    {
        const float4* r4 = (const float4*)(roots + (size_t)b * NR * ND);
        float4* o4 = (float4*)gbuf;
        for (int i = tid; i < NR * ND / 4; i += NTH) o4[i] = r4[i];
        for (int i = tid; i < 2 * NN; i += NTH) parv[i] = (unsigned short)gi[i];
        for (int i = tid; i < NN; i += NTH) depth[i] = (i < NR) ? 0u : 0xFFFFFFFFu;
        for (int i = tid; i < NN; i += NTH) scanA[i] = 0;
        if (tid == 0) s_maxd = 0;
    }
    __syncthreads();

    // ---- depth: single-wave propagation over 64-node groups ----
    if (w == 0) {
        for (int g0 = NR; g0 < NN; g0 += 64) {
            const int n  = g0 + lane;
            const int p0 = parv[2 * n];
            const int p1 = parv[2 * n + 1];
            bool done = false;
            #pragma unroll 1
            for (int iter = 0; iter < 64; ++iter) {
                if (!done) {
                    const unsigned d0 = depth[p0];
                    const unsigned d1 = depth[p1];
                    if (d0 != 0xFFFFFFFFu && d1 != 0xFFFFFFFFu) {
                        depth[n] = 1u + (d0 > d1 ? d0 : d1);
                        done = true;
                    }
                }
                if (__all(done)) break;
                asm volatile("s_waitcnt lgkmcnt(0)" ::: "memory");
            }
        }
    }
    __syncthreads();

    // ---- keys + histogram + maxd ----
    {
        unsigned mloc = 0;
        for (int i = tid; i < NN; i += NTH) {
            if (i >= NR) {
                unsigned lv = depth[i]; if (lv > 255u) lv = 255u;
                if (lv > mloc) mloc = lv;
                int key = (int)lv * 8 + gtyp[i];
                keys[i] = (unsigned short)key;
                atomicAdd(&scanA[key], 1u);
            }
        }
        atomicMax(&s_maxd, (int)mloc);
    }
    __syncthreads();

    // ---- inclusive scan of bucket counts (in place) ----
    block_scan2048(scanA, csum, w, lane);

    // scatter cursors (exclusive offsets)
    for (int i = tid; i < NN; i += NTH) curs[i] = (i == 0) ? 0u : scanA[i - 1];
    __syncthreads();

    // ---- scatter: list + listP; repurpose keys[] as node->listpos ----
    for (int i = tid; i < NN; i += NTH) {
        if (i >= NR) {
            unsigned p = atomicAdd(&curs[keys[i]], 1u);
            list[p]  = (unsigned short)i;
            listP[p] = ((const unsigned*)parv)[i];
            keys[i]  = (unsigned short)p;
        }
    }
    __syncthreads();

    // ---- preload this wave's type weights + biases into registers ----
    short8 w1f[32];
    #pragma unroll
    for (int n0 = 0; n0 < 8; ++n0)
        #pragma unroll
        for (int kk = 0; kk < 4; ++kk)
            w1f[n0 * 4 + kk] = *(const short8*)(w1t +
                ((size_t)(w * 128 + n0 * 16 + l) * 128 + kk * 32 + q * 8));
    short8 w2f[16];
    #pragma unroll
    for (int n0 = 0; n0 < 4; ++n0)
        #pragma unroll
        for (int kk = 0; kk < 4; ++kk)
            w2f[n0 * 4 + kk] = *(const short8*)(w2t +
                ((size_t)(w * 64 + n0 * 16 + l) * 128 + kk * 32 + q * 8));
    float bv1[8], bv2[4];
    #pragma unroll
    for (int n = 0; n < 8; ++n) bv1[n] = b1[w * 128 + n * 16 + l];
    #pragma unroll
    for (int n = 0; n < 4; ++n) bv2[n] = b2[w * 64 + n * 16 + l];

    // prefetch state (carried across levels)
    float4 pf[8];
    bool pff0 = false, pff1 = false;

    // ---- execute levels: wave w handles bucket (L, type=w) ----
    const int maxd = s_maxd;
    for (int L = 1; L <= maxd; ++L) {
        const int key = L * 8 + w;
        const unsigned seg = scanA[key - 1];
        const int cnt = (int)(scanA[key] - seg);
        const unsigned lvlbaseCur  = scanA[L * 8 - 1];
        const unsigned lvlbasePrev = (L >= 2) ? scanA[L * 8 - 9] : 0u;

        for (int r0 = 0; r0 < cnt; r0 += 16) {
            const int rows = min(16, cnt - r0);
            const bool usePF = (r0 == 0) && (L >= 2);

            // ---- gather A-fragments ----
            const int rr = min(l, rows - 1);
            const unsigned pcat = listP[seg + r0 + rr];
            const int p0 = (int)(pcat & 0xFFFFu), p1 = (int)(pcat >> 16);

            short8 af[4];
            // parent 0 -> af[0..1]
            {
                bool hot = false; int slot = 0;
                if (p0 >= NR && depth[p0] == (unsigned)(L - 1)) {
                    slot = (int)keys[p0] - (int)lvlbasePrev;
                    hot = (slot < SROWS);
                }
                if (hot) {
                    const unsigned short* sp = &stash[(L - 1) & 1][slot][0];
                    af[0] = *(const short8*)(sp + q * 8);
                    af[1] = *(const short8*)(sp + 32 + q * 8);
                } else if (usePF && pff0) {
                    af[0] = cvt8(pf[0], pf[1]);
                    af[1] = cvt8(pf[2], pf[3]);
                } else {
                    const float* s = gbuf + (size_t)p0 * 64 + q * 8;
                    af[0] = cvt8(*(const float4*)s,        *(const float4*)(s + 4));
                    af[1] = cvt8(*(const float4*)(s + 32), *(const float4*)(s + 36));
                }
            }
            // parent 1 -> af[2..3]
            {
                bool hot = false; int slot = 0;
                if (p1 >= NR && depth[p1] == (unsigned)(L - 1)) {
                    slot = (int)keys[p1] - (int)lvlbasePrev;
                    hot = (slot < SROWS);
                }
                if (hot) {
                    const unsigned short* sp = &stash[(L - 1) & 1][slot][0];
                    af[2] = *(const short8*)(sp + q * 8);
                    af[3] = *(const short8*)(sp + 32 + q * 8);
                } else if (usePF && pff1) {
                    af[2] = cvt8(pf[4], pf[5]);
                    af[3] = cvt8(pf[6], pf[7]);
                } else {
                    const float* s = gbuf + (size_t)p1 * 64 + q * 8;
                    af[2] = cvt8(*(const float4*)s,        *(const float4*)(s + 4));
                    af[3] = cvt8(*(const float4*)(s + 32), *(const float4*)(s + 36));
                }
            }

            // ---- layer 1 (two 64-col halves; weights in regs) ----
            #pragma unroll
            for (int h = 0; h < 2; ++h) {
                f32x4 c1[4];
                #pragma unroll
                for (int n0 = 0; n0 < 4; ++n0) c1[n0] = (f32x4){0.f, 0.f, 0.f, 0.f};
                #pragma unroll
                for (int kk = 0; kk < 4; ++kk)
                    #pragma unroll
                    for (int n0 = 0; n0 < 4; ++n0)
                        c1[n0] = __builtin_amdgcn_mfma_f32_16x16x32_bf16(
                            af[kk], w1f[(h * 4 + n0) * 4 + kk], c1[n0], 0, 0, 0);

                #pragma unroll
                for (int n0 = 0; n0 < 4; ++n0) {
                    const float bv = bv1[h * 4 + n0];
                    #pragma unroll
                    for (int rg = 0; rg < 4; ++rg) {
                        const float v = c1[n0][rg] + bv;
                        hs[w][q * 4 + rg][(h * 4 + n0) * 16 + l] = f2bf(fast_gelu(v));
                    }
                }
            }
            asm volatile("s_waitcnt lgkmcnt(0)" ::: "memory");

            // ---- layer 2 ----
            short8 a2[4];
            #pragma unroll
            for (int kk = 0; kk < 4; ++kk)
                a2[kk] = *(const short8*)&hs[w][l][kk * 32 + q * 8];
            f32x4 c2[4];
            #pragma unroll
            for (int n0 = 0; n0 < 4; ++n0) c2[n0] = (f32x4){0.f, 0.f, 0.f, 0.f};
            #pragma unroll
            for (int kk = 0; kk < 4; ++kk)
                #pragma unroll
                for (int n0 = 0; n0 < 4; ++n0)
                    c2[n0] = __builtin_amdgcn_mfma_f32_16x16x32_bf16(
                        a2[kk], w2f[n0 * 4 + kk], c2[n0], 0, 0, 0);

            // ---- epilogue: +b2, store fp32 + bf16 frontier stash ----
            const int slotB = (int)(seg - lvlbaseCur) + r0;
            #pragma unroll
            for (int n0 = 0; n0 < 4; ++n0) {
                const float bv = bv2[n0];
                #pragma unroll
                for (int rg = 0; rg < 4; ++rg) {
                    const int row = q * 4 + rg;
                    if (row < rows) {
                        const int nd = list[seg + r0 + row];
                        const float val = c2[n0][rg] + bv;
                        gbuf[nd * 64 + n0 * 16 + l] = val;
                        const int sw = slotB + row;
                        if (sw < SROWS)
                            stash[L & 1][sw][n0 * 16 + l] = f2bf(val);
                    }
                }
            }
        }

        // ---- prefetch cold parents of next level's first tile ----
        pff0 = pff1 = false;
        if (L + 1 <= maxd) {
            const int keyN = key + 8;
            const unsigned segN = scanA[keyN - 1];
            const int cntN = (int)(scanA[keyN] - segN);
            if (cntN > 0) {
                const int rrN = min(l, min(cntN, 16) - 1);
                const unsigned pcatN = listP[segN + rrN];
                const int pn0 = (int)(pcatN & 0xFFFFu), pn1 = (int)(pcatN >> 16);
                const unsigned dn0 = (pn0 >= NR) ? depth[pn0] : 0u;
                const unsigned dn1 = (pn1 >= NR) ? depth[pn1] : 0u;
                if (dn0 <= (unsigned)(L - 1)) {   // final before this level
                    const float* s = gbuf + (size_t)pn0 * 64 + q * 8;
                    pf[0] = *(const float4*)s;        pf[1] = *(const float4*)(s + 4);
                    pf[2] = *(const float4*)(s + 32); pf[3] = *(const float4*)(s + 36);
                    pff0 = true;
                }
                if (dn1 <= (unsigned)(L - 1)) {
                    const float* s = gbuf + (size_t)pn1 * 64 + q * 8;
                    pf[4] = *(const float4*)s;        pf[5] = *(const float4*)(s + 4);
                    pf[6] = *(const float4*)(s + 32); pf[7] = *(const float4*)(s + 36);
                    pff1 = true;
                }
            }
        }
        __syncthreads();   // level boundary (drains stores before next gather)
    }
}

extern "C" void kernel_launch(void* const* d_in, const int* in_sizes, int n_in,
                              void* d_out, int out_size, void* d_ws, size_t ws_size,
                              hipStream_t stream) {
    const float* roots = (const float*)d_in[0];
    const float* W1    = (const float*)d_in[1];
    const float* b1    = (const float*)d_in[2];
    const float* W2    = (const float*)d_in[3];
    const float* b2    = (const float*)d_in[4];
    const int*   idxs  = (const int*)d_in[5];
    const int*   types = (const int*)d_in[6];
    float*       outp  = (float*)d_out;

    unsigned short* w1t = (unsigned short*)d_ws;        // 256 KB
    unsigned short* w2t = w1t + NT * 128 * 128;         // 128 KB

    convert_weights<<<dim3(512), dim3(256), 0, stream>>>(W1, W2, w1t, w2t);
    dag_encoder_kernel<<<dim3(NB), dim3(NTH), 0, stream>>>(
        roots, b1, b2, idxs, types, outp, w1t, w2t);
}

// Round 11
// 423.623 us; speedup vs baseline: 1.1362x; 1.1362x over previous
//
#include <hip/hip_runtime.h>
#include <hip/hip_bf16.h>
#include <math.h>

// Problem constants
#define NB 256   // graphs
#define NN 2048  // nodes
#define NR 64    // roots
#define ND 64    // embed dim
#define NT 8     // node types
#define NTH 512  // threads per block (8 waves: one wave per node type)
#define NW 8     // waves per block
#define XP 136   // hs row stride in shorts (272 B: 16B-aligned, conflict-benign)

typedef __attribute__((ext_vector_type(8))) short short8;
typedef __attribute__((ext_vector_type(4))) float f32x4;

__device__ __forceinline__ unsigned short f2bf(float f) {
    unsigned u = __float_as_uint(f);
    return (unsigned short)((u + 0x7fffu + ((u >> 16) & 1u)) >> 16);
}

// Packed RNE f32x2 -> bf16x2 (v_cvt_pk_bf16_f32; bit-identical to f2bf pairs).
__device__ __forceinline__ unsigned pk2bf(float a, float b) {
    __hip_bfloat162 h = __float22bfloat162_rn(float2{a, b});
    unsigned r; __builtin_memcpy(&r, &h, 4); return r;
}

__device__ __forceinline__ short8 cvt8(float4 a, float4 b) {
    union { short8 s; unsigned u[4]; } v;
    v.u[0] = pk2bf(a.x, a.y); v.u[1] = pk2bf(a.z, a.w);
    v.u[2] = pk2bf(b.x, b.y); v.u[3] = pk2bf(b.z, b.w);
    return v.s;
}

// Fast GELU via A&S 7.1.25 3-term erf (|err| <= 2.5e-5 — invisible under
// bf16-weight quantization noise).
__device__ __forceinline__ float fast_gelu(float v) {
    const float ax = fabsf(v) * 0.70710678118654752f;
    const float t  = __builtin_amdgcn_rcpf(fmaf(0.47047f, ax, 1.0f));
    float p = fmaf(0.7478556f, t, -0.0958798f);
    p = fmaf(p, t, 0.3480242f);
    p *= t;
    const float e  = exp2f(ax * ax * -1.4426950408889634f); // exp(-x^2)
    const float er = fmaf(-p, e, 1.0f);                     // erf(|x|)
    const float es = copysignf(er, v);
    const float hv = 0.5f * v;
    return fmaf(hv, es, hv);                                // 0.5v(1+erf)
}

// Fire-and-forget global->LDS DMA, 16B/lane (dest = uniform base + lane*16).
__device__ __forceinline__ void gl_lds16(const float* g, float* l) {
    __builtin_amdgcn_global_load_lds(
        (const __attribute__((address_space(1))) void*)g,
        (__attribute__((address_space(3))) void*)l, 16, 0, 0);
}

// ---------------------------------------------------------------------------
// Pre-kernel: transpose weights to [type][out][in] bf16 (RNE).
// ---------------------------------------------------------------------------
__global__ void convert_weights(const float* __restrict__ W1,
                                const float* __restrict__ W2,
                                unsigned short* __restrict__ w1t,
                                unsigned short* __restrict__ w2t) {
    int g = blockIdx.x * 256 + threadIdx.x;
    if (g < NT * 128 * 128) {
        int t = g >> 14, r = g & 16383, j = r >> 7, i = r & 127;
        w1t[g] = f2bf(W1[(t * 128 + i) * 128 + j]);
    }
    if (g < NT * 64 * 128) {
        int t = g >> 13, r = g & 8191, d = r >> 7, jj = r & 127;
        w2t[g] = f2bf(W2[(t * 128 + jj) * 64 + d]);
    }
}

// Inclusive block scan of arr[0..2048) via wave shuffles: 3 barriers.
__device__ __forceinline__ void block_scan2048(unsigned* __restrict__ arr,
                                               unsigned* __restrict__ csum,
                                               int w, int lane) {
    for (int c = w; c < 32; c += NW) {
        unsigned v = arr[c * 64 + lane];
        #pragma unroll
        for (int off = 1; off < 64; off <<= 1) {
            unsigned u = __shfl_up(v, off, 64);
            if (lane >= off) v += u;
        }
        arr[c * 64 + lane] = v;
        if (lane == 63) csum[c] = v;
    }
    __syncthreads();
    if (w == 0) {
        unsigned s = (lane < 32) ? csum[lane] : 0u;
        #pragma unroll
        for (int off = 1; off < 32; off <<= 1) {
            unsigned u = __shfl_up(s, off, 64);
            if (lane >= off) s += u;
        }
        if (lane < 32) csum[lane] = s;
    }
    __syncthreads();
    for (int c = w; c < 32; c += NW)
        if (c > 0) arr[c * 64 + lane] += csum[c - 1];
    __syncthreads();
}

// ---------------------------------------------------------------------------
// One block (512 thr, 8 waves) per graph. Wave w owns node type t=w (weights
// + biases register-resident). Per level, wave w processes bucket key=L*8+w.
// Cold parents (depth <= L-2) of the next level's first tile are DMA'd into
// pfbuf via global_load_lds at end-of-level (no registers live across the
// barrier — the R9 scratch-spill lesson); hot parents (depth == L-1) load
// from gbuf (L2-hot). pfbuf source/read pair is XOR-swizzled (chunk ^ row&7)
// to spread the stride-256B consume across bank quads.
// ---------------------------------------------------------------------------
__global__ __launch_bounds__(NTH, 2)
void dag_encoder_kernel(const float* __restrict__ roots,
                        const float* __restrict__ b1,
                        const float* __restrict__ b2,
                        const int*   __restrict__ idxs,
                        const int*   __restrict__ types,
                        float* __restrict__ out,
                        const unsigned short* __restrict__ w1t,
                        const unsigned short* __restrict__ w2t)
{
    __shared__ unsigned int   depth[NN];        // 8 KB (preserved through exec)
    __shared__ unsigned short keys[NN];         // 4 KB
    __shared__ unsigned int   scanA[NN];        // 8 KB (inclusive key-count scan)
    __shared__ unsigned int   curs[NN];         // 8 KB (scatter cursors)
    __shared__ unsigned short list[NN];         // 4 KB (nodes sorted by key)
    __shared__ unsigned int   listP[NN];        // 8 KB (parent pairs, key-sorted)
    __shared__ __align__(4) unsigned short parv[2 * NN];  // 8 KB
    __shared__ unsigned int   csum[32];
    __shared__ __align__(16) unsigned short hs[NW][16][XP];   // 34 KB
    __shared__ __align__(16) float pfbuf[NW][2][16][64];      // 64 KB prefetch
    __shared__ int s_maxd;

    const int b    = blockIdx.x;
    const int tid  = threadIdx.x;
    const int w    = tid >> 6;     // wave id == owned node type
    const int lane = tid & 63;
    const int q    = lane >> 4;
    const int l    = lane & 15;

    float* gbuf = out + (size_t)b * NN * ND;
    const int* gtyp = types + (size_t)b * NN;
    const int* gi   = idxs  + (size_t)b * NN * 2;

    // ---- roots -> gbuf; parents -> LDS; depth init ----
    {
        const float4* r4 = (const float4*)(roots + (size_t)b * NR * ND);
        float4* o4 = (float4*)gbuf;
        for (int i = tid; i < NR * ND / 4; i += NTH) o4[i] = r4[i];
        for (int i = tid; i < 2 * NN; i += NTH) parv[i] = (unsigned short)gi[i];
        for (int i = tid; i < NN; i += NTH) depth[i] = (i < NR) ? 0u : 0xFFFFFFFFu;
        for (int i = tid; i < NN; i += NTH) scanA[i] = 0;
        if (tid == 0) s_maxd = 0;
    }
    __syncthreads();

    // ---- depth: single-wave propagation over 64-node groups ----
    if (w == 0) {
        for (int g0 = NR; g0 < NN; g0 += 64) {
            const int n  = g0 + lane;
            const int p0 = parv[2 * n];
            const int p1 = parv[2 * n + 1];
            bool done = false;
            #pragma unroll 1
            for (int iter = 0; iter < 64; ++iter) {
                if (!done) {
                    const unsigned d0 = depth[p0];
                    const unsigned d1 = depth[p1];
                    if (d0 != 0xFFFFFFFFu && d1 != 0xFFFFFFFFu) {
                        depth[n] = 1u + (d0 > d1 ? d0 : d1);
                        done = true;
                    }
                }
                if (__all(done)) break;
                asm volatile("s_waitcnt lgkmcnt(0)" ::: "memory");
            }
        }
    }
    __syncthreads();

    // ---- keys + histogram + maxd ----
    {
        unsigned mloc = 0;
        for (int i = tid; i < NN; i += NTH) {
            if (i >= NR) {
                unsigned lv = depth[i]; if (lv > 255u) lv = 255u;
                if (lv > mloc) mloc = lv;
                int key = (int)lv * 8 + gtyp[i];
                keys[i] = (unsigned short)key;
                atomicAdd(&scanA[key], 1u);
            }
        }
        atomicMax(&s_maxd, (int)mloc);
    }
    __syncthreads();

    // ---- inclusive scan of bucket counts (in place) ----
    block_scan2048(scanA, csum, w, lane);

    // scatter cursors (exclusive offsets); depth[] stays intact
    for (int i = tid; i < NN; i += NTH) curs[i] = (i == 0) ? 0u : scanA[i - 1];
    __syncthreads();

    // ---- scatter nodes into list (sorted by key), parents into listP ----
    for (int i = tid; i < NN; i += NTH) {
        if (i >= NR) {
            unsigned p = atomicAdd(&curs[keys[i]], 1u);
            list[p]  = (unsigned short)i;
            listP[p] = ((const unsigned*)parv)[i];
        }
    }
    __syncthreads();

    // ---- preload this wave's type weights + biases into registers ----
    short8 w1f[32];
    #pragma unroll
    for (int n0 = 0; n0 < 8; ++n0)
        #pragma unroll
        for (int kk = 0; kk < 4; ++kk)
            w1f[n0 * 4 + kk] = *(const short8*)(w1t +
                ((size_t)(w * 128 + n0 * 16 + l) * 128 + kk * 32 + q * 8));
    short8 w2f[16];
    #pragma unroll
    for (int n0 = 0; n0 < 4; ++n0)
        #pragma unroll
        for (int kk = 0; kk < 4; ++kk)
            w2f[n0 * 4 + kk] = *(const short8*)(w2t +
                ((size_t)(w * 64 + n0 * 16 + l) * 128 + kk * 32 + q * 8));
    float bv1[8], bv2[4];
    #pragma unroll
    for (int n = 0; n < 8; ++n) bv1[n] = b1[w * 128 + n * 16 + l];
    #pragma unroll
    for (int n = 0; n < 4; ++n) bv2[n] = b2[w * 64 + n * 16 + l];

    // ---- execute levels: wave w handles bucket (L, type=w) ----
    const int maxd = s_maxd;
    for (int L = 1; L <= maxd; ++L) {
        const int key = L * 8 + w;
        const unsigned seg = scanA[key - 1];
        const int cnt = (int)(scanA[key] - seg);

        for (int r0 = 0; r0 < cnt; r0 += 16) {
            const int rows = min(16, cnt - r0);
            const bool usePF = (L >= 2) && (r0 == 0);

            // ---- gather A-fragments: pfbuf (cold) / gbuf (hot) ----
            const int rr = min(l, rows - 1);
            const unsigned pcat = listP[seg + r0 + rr];
            const int p0 = (int)(pcat & 0xFFFFu), p1 = (int)(pcat >> 16);
            const int sx = l & 7;

            short8 af[4];
            {
                const bool hot = !usePF || (depth[p0] == (unsigned)(L - 1));
                if (hot) {
                    const float* s = gbuf + (size_t)p0 * 64 + q * 8;
                    af[0] = cvt8(*(const float4*)s,        *(const float4*)(s + 4));
                    af[1] = cvt8(*(const float4*)(s + 32), *(const float4*)(s + 36));
                } else {
                    const float4* pb = (const float4*)&pfbuf[w][0][l][0];
                    af[0] = cvt8(pb[(2 * q) ^ sx],     pb[(2 * q + 1) ^ sx]);
                    af[1] = cvt8(pb[(8 + 2 * q) ^ sx], pb[(8 + 2 * q + 1) ^ sx]);
                }
            }
            {
                const bool hot = !usePF || (depth[p1] == (unsigned)(L - 1));
                if (hot) {
                    const float* s = gbuf + (size_t)p1 * 64 + q * 8;
                    af[2] = cvt8(*(const float4*)s,        *(const float4*)(s + 4));
                    af[3] = cvt8(*(const float4*)(s + 32), *(const float4*)(s + 36));
                } else {
                    const float4* pb = (const float4*)&pfbuf[w][1][l][0];
                    af[2] = cvt8(pb[(2 * q) ^ sx],     pb[(2 * q + 1) ^ sx]);
                    af[3] = cvt8(pb[(8 + 2 * q) ^ sx], pb[(8 + 2 * q + 1) ^ sx]);
                }
            }

            // ---- layer 1 h=0 + interleaved layer-2 kk={0,1} ----
            f32x4 c2[4];
            #pragma unroll
            for (int n0 = 0; n0 < 4; ++n0) c2[n0] = (f32x4){0.f, 0.f, 0.f, 0.f};
            {
                f32x4 c1[4];
                #pragma unroll
                for (int n0 = 0; n0 < 4; ++n0) c1[n0] = (f32x4){0.f, 0.f, 0.f, 0.f};
                #pragma unroll
                for (int kk = 0; kk < 4; ++kk)
                    #pragma unroll
                    for (int n0 = 0; n0 < 4; ++n0)
                        c1[n0] = __builtin_amdgcn_mfma_f32_16x16x32_bf16(
                            af[kk], w1f[n0 * 4 + kk], c1[n0], 0, 0, 0);
                #pragma unroll
                for (int n0 = 0; n0 < 4; ++n0) {
                    const float bv = bv1[n0];
                    #pragma unroll
                    for (int rg = 0; rg < 4; ++rg) {
                        const float v = c1[n0][rg] + bv;
                        hs[w][q * 4 + rg][n0 * 16 + l] = f2bf(fast_gelu(v));
                    }
                }
            }
            asm volatile("s_waitcnt lgkmcnt(0)" ::: "memory");
            {
                const short8 a20 = *(const short8*)&hs[w][l][q * 8];
                const short8 a21 = *(const short8*)&hs[w][l][32 + q * 8];
                #pragma unroll
                for (int n0 = 0; n0 < 4; ++n0) {
                    c2[n0] = __builtin_amdgcn_mfma_f32_16x16x32_bf16(
                        a20, w2f[n0 * 4 + 0], c2[n0], 0, 0, 0);
                    c2[n0] = __builtin_amdgcn_mfma_f32_16x16x32_bf16(
                        a21, w2f[n0 * 4 + 1], c2[n0], 0, 0, 0);
                }
            }

            // ---- layer 1 h=1 + layer-2 kk={2,3} ----
            {
                f32x4 c1[4];
                #pragma unroll
                for (int n0 = 0; n0 < 4; ++n0) c1[n0] = (f32x4){0.f, 0.f, 0.f, 0.f};
                #pragma unroll
                for (int kk = 0; kk < 4; ++kk)
                    #pragma unroll
                    for (int n0 = 0; n0 < 4; ++n0)
                        c1[n0] = __builtin_amdgcn_mfma_f32_16x16x32_bf16(
                            af[kk], w1f[(4 + n0) * 4 + kk], c1[n0], 0, 0, 0);
                #pragma unroll
                for (int n0 = 0; n0 < 4; ++n0) {
                    const float bv = bv1[4 + n0];
                    #pragma unroll
                    for (int rg = 0; rg < 4; ++rg) {
                        const float v = c1[n0][rg] + bv;
                        hs[w][q * 4 + rg][(4 + n0) * 16 + l] = f2bf(fast_gelu(v));
                    }
                }
            }
            asm volatile("s_waitcnt lgkmcnt(0)" ::: "memory");
            {
                const short8 a22 = *(const short8*)&hs[w][l][64 + q * 8];
                const short8 a23 = *(const short8*)&hs[w][l][96 + q * 8];
                #pragma unroll
                for (int n0 = 0; n0 < 4; ++n0) {
                    c2[n0] = __builtin_amdgcn_mfma_f32_16x16x32_bf16(
                        a22, w2f[n0 * 4 + 2], c2[n0], 0, 0, 0);
                    c2[n0] = __builtin_amdgcn_mfma_f32_16x16x32_bf16(
                        a23, w2f[n0 * 4 + 3], c2[n0], 0, 0, 0);
                }
            }

            // ---- epilogue: +b2, scatter store ----
            #pragma unroll
            for (int n0 = 0; n0 < 4; ++n0) {
                const float bv = bv2[n0];
                #pragma unroll
                for (int rg = 0; rg < 4; ++rg) {
                    const int row = q * 4 + rg;
                    if (row < rows) {
                        const int nd = list[seg + r0 + row];
                        gbuf[nd * 64 + n0 * 16 + l] = c2[n0][rg] + bv;
                    }
                }
            }
        }

        // ---- refill pfbuf for next level's first tile (async DMA; lands
        // before consume after the barrier; runs even if wave had no tiles).
        // Cold parents only (depth <= L-1: final, race-free vs in-flight
        // stores). Per-lane source XOR-swizzle (chunk ^ row&7); LDS linear.
        if (L < maxd) {
            const int keyN = key + 8;
            const unsigned segN = scanA[keyN - 1];
            const int cntN = (int)(scanA[keyN] - segN);
            if (cntN > 0) {
                asm volatile("s_waitcnt lgkmcnt(0)" ::: "memory"); // pfbuf reads retired
                const int r = lane >> 4;          // row within 4-row group
                const int c = lane & 15;          // 16B chunk within row
                #pragma unroll
                for (int g = 0; g < 4; ++g) {
                    const int rowg = g * 4 + r;
                    const int rc = min(rowg, cntN - 1);
                    const unsigned pc = listP[segN + rc];
                    const int pa = (int)(pc & 0xFFFFu);
                    const int pb = (int)(pc >> 16);
                    const int co = (c ^ (rowg & 7)) * 4;   // swizzled float offset
                    if (depth[pa] <= (unsigned)(L - 1))
                        gl_lds16(gbuf + (size_t)pa * 64 + co, &pfbuf[w][0][g * 4][0]);
                    if (depth[pb] <= (unsigned)(L - 1))
                        gl_lds16(gbuf + (size_t)pb * 64 + co, &pfbuf[w][1][g * 4][0]);
                }
            }
        }
        __syncthreads();   // level boundary (drains stores + DMA before next gather)
    }
}

extern "C" void kernel_launch(void* const* d_in, const int* in_sizes, int n_in,
                              void* d_out, int out_size, void* d_ws, size_t ws_size,
                              hipStream_t stream) {
    const float* roots = (const float*)d_in[0];
    const float* W1    = (const float*)d_in[1];
    const float* b1    = (const float*)d_in[2];
    const float* W2    = (const float*)d_in[3];
    const float* b2    = (const float*)d_in[4];
    const int*   idxs  = (const int*)d_in[5];
    const int*   types = (const int*)d_in[6];
    float*       outp  = (float*)d_out;

    unsigned short* w1t = (unsigned short*)d_ws;        // 256 KB
    unsigned short* w2t = w1t + NT * 128 * 128;         // 128 KB

    convert_weights<<<dim3(512), dim3(256), 0, stream>>>(W1, W2, w1t, w2t);
    dag_encoder_kernel<<<dim3(NB), dim3(NTH), 0, stream>>>(
        roots, b1, b2, idxs, types, outp, w1t, w2t);
}